// Round 12
// baseline (246.333 us; speedup 1.0000x reference)
//
#include <hip/hip_runtime.h>
#include <math.h>

#define HW_     (1024 * 1024)
#define NPIX    (4 * HW_)               // 4,194,304 pixels
#define NG      (NPIX / 4)              // 1,048,576 float4 groups
#define BLOCK_  256
#define TILE_G  1024                    // groups per block tile (16 KB/plane/block)
#define RUN     4                       // consecutive 1KB wave-loads per plane
#define GRID1   (NG / TILE_G)           // 1024 blocks (R10 config: proven best)
#define SLOTS   32                      // per-block partial row: 0..7 sx, 8..15 sy,
                                        // 16..23 cnt, 24 spw, 25 sxx, 26..31 zero

// Native clang vector type: __builtin_nontemporal_load requires a pointer to
// scalar/pointer/VECTOR type -- HIP_vector_type (float4) is rejected.
typedef float f32x4 __attribute__((ext_vector_type(4)));

// fast pow for x>0: v_log_f32 (log2) + v_mul + v_exp_f32 (exp2)
__device__ __forceinline__ float fast_pow_pos(float x, float p) {
    return __builtin_amdgcn_exp2f(p * __builtin_amdgcn_logf(x));
}

// Round 12: R10 (best measured, e2e 241.1) + dispatch-count cleanup.
// Ledger: churn-limited regime (R0-R8) fixed by all-nt streaming (R9/R10:
// 2.46 -> ~3.4 TB/s). R11 falsified concurrency scaling in the streaming
// regime (8 blocks/CU slightly worse). This round keeps R10's pass1 verbatim
// (nt loads, plane-major, sched_barrier-pinned plane batches, RUN=4, 1024
// blocks) and removes self-inflicted overhead: per-block slot writes replace
// device-scope double atomics, which also removes the hipMemsetAsync dispatch
// (every slot fully overwritten each run -> re-poison-proof).
__global__ __launch_bounds__(BLOCK_, 4) void pass1_kernel(
    const float* __restrict__ x, const float* __restrict__ y,
    const float* __restrict__ mk, float* __restrict__ part)
{
    const int tid  = threadIdx.x;
    const int wave = tid >> 6, lane = tid & 63;
    const int t    = blockIdx.x;            // 0..1023
    const int b    = t >> 8;                // 256 tiles per batch
    // float offset of this thread's r=0 chunk inside a plane:
    const size_t hw0 = (size_t)(t & 255) * 4096 + (size_t)wave * 1024
                     + (size_t)lane * 4;

    const float* xp = x  + (size_t)(b * 3) * HW_ + hw0;
    const float* yp = y  + (size_t)(b * 3) * HW_ + hw0;
    const float* mp = mk + (size_t)(b * 8) * HW_ + hw0;

    // ---- x planes: plane-major, 4KB contiguous per wave per plane ----
    f32x4 xs[RUN], ys[RUN];
#pragma unroll
    for (int r = 0; r < RUN; ++r)
        xs[r] = __builtin_nontemporal_load((const f32x4*)(xp + r * 256));
#pragma unroll
    for (int c = 1; c < 3; ++c) {
        __builtin_amdgcn_sched_barrier(0);  // keep plane batches in order
#pragma unroll
        for (int r = 0; r < RUN; ++r)
            xs[r] += __builtin_nontemporal_load(
                (const f32x4*)(xp + (size_t)c * HW_ + r * 256));
    }
    __builtin_amdgcn_sched_barrier(0);
    // ---- y planes ----
#pragma unroll
    for (int r = 0; r < RUN; ++r)
        ys[r] = __builtin_nontemporal_load((const f32x4*)(yp + r * 256));
#pragma unroll
    for (int c = 1; c < 3; ++c) {
        __builtin_amdgcn_sched_barrier(0);
#pragma unroll
        for (int r = 0; r < RUN; ++r)
            ys[r] += __builtin_nontemporal_load(
                (const f32x4*)(yp + (size_t)c * HW_ + r * 256));
    }
    const float inv3 = 1.0f / 3.0f;
#pragma unroll
    for (int r = 0; r < RUN; ++r) { xs[r] *= inv3; ys[r] *= inv3; }

    // ---- mask planes: nt plane-major running argmax ----
    // strict >: first occurrence wins (jnp.argmax tie-break, c ascending)
    f32x4 best[RUN]; int4 bi[RUN];
    __builtin_amdgcn_sched_barrier(0);
#pragma unroll
    for (int r = 0; r < RUN; ++r) {
        best[r] = __builtin_nontemporal_load((const f32x4*)(mp + r * 256));
        bi[r].x = 0; bi[r].y = 0; bi[r].z = 0; bi[r].w = 0;
    }
#pragma unroll
    for (int c = 1; c < 8; ++c) {
        __builtin_amdgcn_sched_barrier(0);
#pragma unroll
        for (int r = 0; r < RUN; ++r) {
            const f32x4 v = __builtin_nontemporal_load(
                (const f32x4*)(mp + (size_t)c * HW_ + r * 256));
            if (v.x > best[r].x) { best[r].x = v.x; bi[r].x = c; }
            if (v.y > best[r].y) { best[r].y = v.y; bi[r].y = c; }
            if (v.z > best[r].z) { best[r].z = v.z; bi[r].z = c; }
            if (v.w > best[r].w) { best[r].w = v.w; bi[r].w = c; }
        }
    }

    // ---- accumulate 16 pixels into the 26 per-thread accumulators ----
    float sx[8], sy[8], sc[8];
#pragma unroll
    for (int l = 0; l < 8; ++l) { sx[l] = 0.f; sy[l] = 0.f; sc[l] = 0.f; }
    float spw = 0.f, sxx = 0.f;

#define PIX(R, F)                                                           \
    {                                                                       \
        const float xav = xs[R].F;                                          \
        const float yav = ys[R].F;                                          \
        const int   lab = bi[R].F;                                          \
        _Pragma("unroll")                                                   \
        for (int l = 0; l < 8; ++l) {                                       \
            const bool p = (lab == l);                                      \
            sx[l] += p ? xav : 0.0f;                                        \
            sy[l] += p ? yav : 0.0f;                                        \
            sc[l] += p ? 1.0f : 0.0f;                                       \
        }                                                                   \
        spw += fast_pow_pos(xav, yav);  /* xav>0: mean of uniforms */       \
        sxx += xav * xav;                                                   \
    }

#pragma unroll
    for (int r = 0; r < RUN; ++r) { PIX(r, x) PIX(r, y) PIX(r, z) PIX(r, w) }
#undef PIX

    // ---- wave64 shuffle reduction of the 26 accumulators ----
#pragma unroll
    for (int off = 32; off > 0; off >>= 1) {
#pragma unroll
        for (int l = 0; l < 8; ++l) {
            sx[l] += __shfl_down(sx[l], off);
            sy[l] += __shfl_down(sy[l], off);
            sc[l] += __shfl_down(sc[l], off);
        }
        spw += __shfl_down(spw, off);
        sxx += __shfl_down(sxx, off);
    }
    __shared__ float red[4][26];
    if (lane == 0) {
#pragma unroll
        for (int l = 0; l < 8; ++l) {
            red[wave][l]      = sx[l];
            red[wave][8 + l]  = sy[l];
            red[wave][16 + l] = sc[l];
        }
        red[wave][24] = spw;
        red[wave][25] = sxx;
    }
    __syncthreads();
    // Per-block slot row: no atomics, no memset (all SLOTS overwritten).
    if (tid < SLOTS) {
        float s = 0.0f;
        if (tid < 26)
            s = red[0][tid] + red[1][tid] + red[2][tid] + red[3][tid];
        part[(size_t)blockIdx.x * SLOTS + tid] = s;
    }
}

// ---- finalize: parallel block-partial sum + all three losses in f64 ----
__global__ void finalize_kernel(const float* __restrict__ part,
                                float* __restrict__ out)
{
    // 1024 threads: thread = (seg 0..31) x (slot 0..31).
    const int slot = threadIdx.x & 31;
    const int seg  = threadIdx.x >> 5;
    double s = 0.0;
    for (int k = seg; k < GRID1; k += 32)          // 32 coalesced loads/thread
        s += (double)part[(size_t)k * SLOTS + slot];
    __shared__ double sh[32][33];
    sh[seg][slot] = s;
    __syncthreads();
    __shared__ double tot[32];
    if (threadIdx.x < 32) {
        double v = 0.0;
        for (int g = 0; g < 32; ++g) v += sh[g][threadIdx.x];
        tot[threadIdx.x] = v;
    }
    __syncthreads();
    if (threadIdx.x == 0) {
        const double invN = 1.0 / (double)NPIX;
        double l1 = tot[24];      // sum of pow over on-mask pixels
        double l3 = tot[25];      // sum of xa^2
        double l2 = 0.0;
        for (int l = 0; l < 8; ++l) {
            double SX  = tot[l];
            double XA  = SX * invN;
            double YA  = tot[8 + l] * invN;
            double cnt = tot[16 + l];
            double pw  = pow(XA, YA);
            l2 += pw;
            l1 += ((double)NPIX - cnt) * pw;          // off-mask pow terms
            l3 += cnt * XA * XA - 2.0 * XA * SX;      // per-label variance cross terms
        }
        out[0] = (float)(l1 * invN);
        out[1] = (float)l2;
        out[2] = (float)(l3 * invN);
    }
}

extern "C" void kernel_launch(void* const* d_in, const int* in_sizes, int n_in,
                              void* d_out, int out_size, void* d_ws, size_t ws_size,
                              hipStream_t stream)
{
    const float* x  = (const float*)d_in[0];
    const float* y  = (const float*)d_in[1];
    const float* mk = (const float*)d_in[2];
    float* out  = (float*)d_out;
    float* part = (float*)d_ws;                 // 1024*32*4 = 128 KB, no memset

    pass1_kernel<<<GRID1, BLOCK_, 0, stream>>>(x, y, mk, part);
    finalize_kernel<<<1, 1024, 0, stream>>>(part, out);
}